// Round 1
// 1356.337 us; speedup vs baseline: 1.0093x; 1.0093x over previous
//
#include <hip/hip_runtime.h>
#include <math.h>

// Problem dims (fixed by reference setup_inputs)
#define NN   20000   // nodes
#define BG   128     // graphs
#define EE   320000  // edges
#define FIN  768
#define RAWF 5000
#define KP   5120    // padded raw K (mult of 32)
#define CATK 10240   // padded 2*RAWF
#define HD   256
#define NC   4

typedef __attribute__((ext_vector_type(4))) float          f32x4;
typedef __attribute__((ext_vector_type(8))) unsigned short u16x8;
typedef __attribute__((ext_vector_type(4))) unsigned short u16x4;
typedef __attribute__((ext_vector_type(8))) __bf16         bf16x8;

__device__ __forceinline__ unsigned short f2bf(float f) {
  unsigned u = __float_as_uint(f);
  u += 0x7FFFu + ((u >> 16) & 1u);
  return (unsigned short)(u >> 16);
}
__device__ __forceinline__ float bf2f(unsigned short u) {
  return __uint_as_float((unsigned)u << 16);
}

static inline int ceil_div(int a, int b) { return (a + b - 1) / b; }

// ---------------------------------------------------------------- CSR build
__global__ void count_deg2_k(const int* __restrict__ ei, const int* __restrict__ rei,
                             int* __restrict__ deg1, int* __restrict__ deg2) {
  int i = blockIdx.x * 256 + threadIdx.x;
  if (i < EE) atomicAdd(&deg1[ei[EE + i]], 1);
  else if (i < 2 * EE) atomicAdd(&deg2[rei[i]], 1);  // rei[EE + (i-EE)] == rei[i]
}

__global__ __launch_bounds__(1024) void scan_local_k(const int* __restrict__ deg1,
                                                     const int* __restrict__ deg2,
                                                     int* __restrict__ excl,
                                                     int* __restrict__ bsum, int nb) {
  const int* deg = blockIdx.y ? deg2 : deg1;
  int* ex = excl + (size_t)blockIdx.y * NN;
  int* bs = bsum + (size_t)blockIdx.y * nb;
  __shared__ int wsum[16];
  int t = threadIdx.x, lane = t & 63, w = t >> 6;
  int i = blockIdx.x * 1024 + t;
  int v = (i < NN) ? deg[i] : 0;
  int acc = v;
#pragma unroll
  for (int off = 1; off < 64; off <<= 1) {
    int o = __shfl_up(acc, off, 64);
    if (lane >= off) acc += o;
  }
  if (lane == 63) wsum[w] = acc;
  __syncthreads();
  if (w == 0 && lane < 16) {
    int s = wsum[lane];
#pragma unroll
    for (int off = 1; off < 16; off <<= 1) {
      int o = __shfl_up(s, off, 64);
      if (lane >= off) s += o;
    }
    wsum[lane] = s;
  }
  __syncthreads();
  if (w > 0) acc += wsum[w - 1];
  if (i < NN) ex[i] = acc - v;
  if (t == 1023) bs[blockIdx.x] = acc;
}

// parallel top-level scan: 2 graphs in the two 32-lane halves of one wave
__global__ void scan_tops_k(const int* __restrict__ bsum, int* __restrict__ boff,
                            int* __restrict__ end1, int* __restrict__ end2, int nb) {
  int t = threadIdx.x;           // 64 threads
  int half = t >> 5, idx = t & 31;
  int v = (idx < nb) ? bsum[half * nb + idx] : 0;
  int acc = v;
#pragma unroll
  for (int off = 1; off < 32; off <<= 1) {
    int o = __shfl_up(acc, off, 32);
    if (idx >= off) acc += o;
  }
  if (idx < nb) boff[half * nb + idx] = acc - v;   // exclusive
  if (idx == nb - 1) {
    if (half == 0) *end1 = acc; else *end2 = acc;
  }
}

__global__ __launch_bounds__(1024) void scan_add_k(
    const int* __restrict__ excl, const int* __restrict__ boff,
    const int* __restrict__ deg1, const int* __restrict__ deg2,
    int* __restrict__ rp1, int* __restrict__ rp2,
    int* __restrict__ cur1, int* __restrict__ cur2,
    float* __restrict__ dv1, float* __restrict__ dv2, int nb) {
  int y = blockIdx.y;
  const int* deg = y ? deg2 : deg1;
  int* rp = y ? rp2 : rp1;
  int* cur = y ? cur2 : cur1;
  float* dv = y ? dv2 : dv1;
  int i = blockIdx.x * 1024 + threadIdx.x;
  if (i < NN) {
    int v = excl[(size_t)y * NN + i] + boff[y * nb + blockIdx.x];
    rp[i] = v;
    cur[i] = v;
    dv[i] = rsqrtf((float)(deg[i] + 1));
  }
}

__global__ void scatter_k(const int* __restrict__ ei, const int* __restrict__ rei,
                          int* __restrict__ cur1, int* __restrict__ cur2,
                          int* __restrict__ col1, int* __restrict__ col2) {
  int i = blockIdx.x * 256 + threadIdx.x;
  int y = blockIdx.y;
  if (i < EE) {
    const int* e = y ? rei : ei;
    int* cur = y ? cur2 : cur1;
    int* col = y ? col2 : col1;
    int d = e[EE + i];
    int p = atomicAdd(&cur[d], 1);
    col[p] = e[i];
  }
}

__global__ void segbounds_k(const int* __restrict__ batch, int* __restrict__ s,
                            int* __restrict__ e, int n) {
  int i = blockIdx.x * 256 + threadIdx.x;
  if (i >= n) return;
  int b = batch[i];
  if (i == 0 || batch[i - 1] != b) s[b] = i;
  if (i == n - 1 || batch[i + 1] != b) e[b] = i + 1;
}

// ------------------------------------------------- batched weight transpose
__global__ __launch_bounds__(256) void trans_k(
    const float* __restrict__ i0, unsigned short* __restrict__ o0,   // W1  768x256 ->768
    const float* __restrict__ i1, unsigned short* __restrict__ o1,   // Wc0 5000x256 ->5120
    const float* __restrict__ i2, unsigned short* __restrict__ o2,   // Wc1 256x256
    const float* __restrict__ i3, unsigned short* __restrict__ o3,   // Wc2 256x256
    const float* __restrict__ i4, unsigned short* __restrict__ o4) { // Wl1 10000x512 ->10240
  __shared__ unsigned short tile[32][34];
  int b = blockIdx.x;
  const float* in; unsigned short* out;
  int K, N, Kout, tx, lid;
  if (b < 192)        { in=i0; out=o0; K=768;   N=256; Kout=768;   tx=24;  lid=b; }
  else if (b < 1472)  { in=i1; out=o1; K=5000;  N=256; Kout=5120;  tx=160; lid=b-192; }
  else if (b < 1536)  { in=i2; out=o2; K=256;   N=256; Kout=256;   tx=8;   lid=b-1472; }
  else if (b < 1600)  { in=i3; out=o3; K=256;   N=256; Kout=256;   tx=8;   lid=b-1536; }
  else                { in=i4; out=o4; K=10000; N=512; Kout=10240; tx=320; lid=b-1600; }
  int k0 = (lid % tx) * 32, n0 = (lid / tx) * 32;
  int txx = threadIdx.x & 31, tyy = threadIdx.x >> 5;
#pragma unroll
  for (int r = 0; r < 32; r += 8) {
    int k = k0 + tyy + r, n = n0 + txx;
    float v = (k < K) ? in[(size_t)k * N + n] : 0.f;
    tile[tyy + r][txx] = f2bf(v);
  }
  __syncthreads();
#pragma unroll
  for (int r = 0; r < 32; r += 8) {
    int n = n0 + tyy + r, k = k0 + txx;
    out[(size_t)n * Kout + k] = tile[txx][tyy + r];
  }
}

// data_x fp32 -> (optional) bf16 K-padded copy + fused segment-mean -> cat[:, :5000]
// grid (BG, 20 + 21): y<20 = pool/convert chunks; y>=20 = root-row -> cat right half.
// Pool part: 4 waves stride rows; lane owns 4 cols (f32x4 16B loads).
__global__ __launch_bounds__(256) void conv_pool_k(const float* __restrict__ x,
                                                   unsigned short* __restrict__ xb,
                                                   unsigned short* __restrict__ cat,
                                                   const int* __restrict__ segs,
                                                   const int* __restrict__ sege,
                                                   const int* __restrict__ root) {
  int g = blockIdx.x;
  if (blockIdx.y >= KP / 256) {   // ---- root-cat part (cols 5000..10239)
    int c = (blockIdx.y - KP / 256) * 256 + threadIdx.x;
    if (c < CATK - RAWF) {
      unsigned short v = 0;
      if (c < RAWF) v = f2bf(x[(size_t)root[g] * RAWF + c]);
      cat[(size_t)g * CATK + RAWF + c] = v;
    }
    return;
  }
  __shared__ f32x4 part[4][64];
  int wave = threadIdx.x >> 6, lane = threadIdx.x & 63;
  int c = blockIdx.y * 256 + lane * 4;
  int s = segs[g], e = sege[g];
  bool v4 = (c + 4 <= RAWF);      // RAWF%4==0: vectors are fully valid or fully pad
  f32x4 sum = (f32x4)0.f;
  for (int i = s + wave; i < e; i += 4) {
    f32x4 v = (f32x4)0.f;
    if (v4) v = *(const f32x4*)(x + (size_t)i * RAWF + c);
    if (xb) {
      u16x4 h;
      h[0] = f2bf(v[0]); h[1] = f2bf(v[1]); h[2] = f2bf(v[2]); h[3] = f2bf(v[3]);
      *(u16x4*)(xb + (size_t)i * KP + c) = h;
    }
    sum += v;
  }
  part[wave][lane] = sum;
  __syncthreads();
  if (threadIdx.x < 64 && v4) {
    f32x4 tot = part[0][lane] + part[1][lane] + part[2][lane] + part[3][lane];
    float cnt = (float)(e - s);
    u16x4 o;
    o[0] = f2bf(tot[0] / cnt); o[1] = f2bf(tot[1] / cnt);
    o[2] = f2bf(tot[2] / cnt); o[3] = f2bf(tot[3] / cnt);
    *(u16x4*)(cat + (size_t)g * CATK + c) = o;
  }
}

// ------------------------------------------------------------- MFMA GEMM
// C[M][N] (+)= A[M][K] @ Bt[N][K]bf16, optional per-row scale (escale[row]).
// 128x128x32 tile, 4 waves, register-prefetch pipeline.
// When gridDim.x==2: remap (x,y) so the x-pair of the same A panel lands on
// the SAME XCD (dispatch linear id %8 = XCD; pair ids differ by exactly 8)
// -> second A read is an L2 hit instead of a second HBM/L3 fetch.
template <bool ABF16>
__global__ __launch_bounds__(256) void gemm_k(
    const void* __restrict__ Av, int Astride,
    const unsigned short* __restrict__ Bt, int Bstride,
    float* __restrict__ C, const float* __restrict__ escale,
    int M, int N, int Kreal, int kchunk, int atomic_out) {
  __shared__ unsigned short As[128 * 40];  // pad 32->40: 2-way bank alias only
  __shared__ unsigned short Bs[128 * 40];
  const int tid = threadIdx.x;
  const int lane = tid & 63, wave = tid >> 6;
  const int quad = lane >> 4, l16 = lane & 15;
  const int koff = quad * 8;

  int xt = blockIdx.x, yt = blockIdx.y;
  if (gridDim.x == 2) {
    const int MT = gridDim.y;
    int flat = (yt << 1) | xt;
    int gp = flat >> 4;
    int ybase = gp << 3;
    int rem = MT - ybase;
    int j = flat & 15;
    if (rem >= 8) { xt = j >> 3; yt = ybase + (j & 7); }
    else          { xt = (j >= rem); yt = ybase + (xt ? j - rem : j); }
  }
  const int bn = xt * 128, bm = yt * 128;
  const int wm = (wave >> 1) * 64, wn = (wave & 1) * 64;
  const int kbegin = blockIdx.z * kchunk;
  int kend = kbegin + kchunk; if (kend > Kreal) kend = Kreal;

  const int brow = tid >> 2, bcol = (tid & 3) * 8;      // bf16 16B loads, 2 rounds
  const int arow_f = tid >> 3, acol_f = (tid & 7) * 4;  // f32 16B loads, 4 rounds

  u16x8 pb[2];
  u16x8 pa_b[2];
  f32x4 pa_f[4];

  auto load_tile = [&](int k0) {
#pragma unroll
    for (int i = 0; i < 2; ++i) {
      int gk = k0 + bcol;
      bool ok = ABF16 ? true : (gk + 8 <= kend);  // B K-dim padded for bf16 paths
      u16x8 v = (u16x8)(unsigned short)0;
      if (ok) v = *(const u16x8*)(Bt + (size_t)(bn + i * 64 + brow) * Bstride + gk);
      pb[i] = v;
    }
    if (ABF16) {
      const unsigned short* A = (const unsigned short*)Av;
#pragma unroll
      for (int i = 0; i < 2; ++i) {
        int r = bm + i * 64 + brow;
        u16x8 v = (u16x8)(unsigned short)0;
        if (r < M) v = *(const u16x8*)(A + (size_t)r * Astride + k0 + bcol);
        pa_b[i] = v;
      }
    } else {
      const float* A = (const float*)Av;
#pragma unroll
      for (int i = 0; i < 4; ++i) {
        int r = bm + i * 32 + arow_f;
        int gk = k0 + acol_f;
        f32x4 v = (f32x4)0.f;
        if (r < M && gk + 4 <= kend) v = *(const f32x4*)(A + (size_t)r * Astride + gk);
        pa_f[i] = v;
      }
    }
  };
  auto store_tile = [&]() {
#pragma unroll
    for (int i = 0; i < 2; ++i)
      *(u16x8*)&Bs[(i * 64 + brow) * 40 + bcol] = pb[i];
    if (ABF16) {
#pragma unroll
      for (int i = 0; i < 2; ++i)
        *(u16x8*)&As[(i * 64 + brow) * 40 + bcol] = pa_b[i];
    } else {
#pragma unroll
      for (int i = 0; i < 4; ++i) {
        u16x4 h;
        h[0] = f2bf(pa_f[i][0]); h[1] = f2bf(pa_f[i][1]);
        h[2] = f2bf(pa_f[i][2]); h[3] = f2bf(pa_f[i][3]);
        *(u16x4*)&As[(i * 32 + arow_f) * 40 + acol_f] = h;
      }
    }
  };

  f32x4 acc[4][4] = {};
  load_tile(kbegin);
  for (int k0 = kbegin; k0 < kend; k0 += 32) {
    store_tile();
    __syncthreads();
    int k1 = k0 + 32;
    if (k1 < kend) load_tile(k1);  // prefetch: latency overlaps MFMA below
    u16x8 ar[4], br[4];
#pragma unroll
    for (int i = 0; i < 4; ++i) ar[i] = *(const u16x8*)&As[(wm + i * 16 + l16) * 40 + koff];
#pragma unroll
    for (int j = 0; j < 4; ++j) br[j] = *(const u16x8*)&Bs[(wn + j * 16 + l16) * 40 + koff];
#pragma unroll
    for (int i = 0; i < 4; ++i)
#pragma unroll
      for (int j = 0; j < 4; ++j)
        acc[i][j] = __builtin_amdgcn_mfma_f32_16x16x32_bf16(
            __builtin_bit_cast(bf16x8, ar[i]), __builtin_bit_cast(bf16x8, br[j]),
            acc[i][j], 0, 0, 0);
    __syncthreads();
  }
  // epilogue: D[row=quad*4+rr][col=l16] (m89/m91-verified mapping)
#pragma unroll
  for (int i = 0; i < 4; ++i)
#pragma unroll
    for (int rr = 0; rr < 4; ++rr) {
      int grow = bm + wm + i * 16 + quad * 4 + rr;
      if (grow >= M) continue;
      float sc = escale ? escale[grow] : 1.f;
#pragma unroll
      for (int j = 0; j < 4; ++j) {
        int gcol = bn + wn + j * 16 + l16;
        if (gcol >= N) continue;
        float v = acc[i][j][rr] * sc;
        if (atomic_out) atomicAdd(&C[(size_t)grow * N + gcol], v);
        else C[(size_t)grow * N + gcol] = v;
      }
    }
}

// ------------------------------------------------------------ GCN aggregate
// h is PRE-SCALED by dinv in the GEMM epilogue: h' = dinv .* (x@W).
// out[i] = relu(dinv[i]*(h'[i] + sum_in h'[s]) + bias), bf16 out.
__global__ __launch_bounds__(256) void gcn_agg_k(
    const float* __restrict__ h, const int* __restrict__ rowptr,
    const int* __restrict__ col, const float* __restrict__ dinv,
    const float* __restrict__ bias, unsigned short* __restrict__ outb, int n) {
  int wave = threadIdx.x >> 6, lane = threadIdx.x & 63;
  int node = blockIdx.x * 4 + wave;
  if (node >= n) return;
  int f = lane * 4;
  f32x4 acc = *(const f32x4*)(h + (size_t)node * HD + f);  // self loop (pre-scaled)
  int beg = rowptr[node], end = rowptr[node + 1];
  int e = beg;
  for (; e + 4 <= end; e += 4) {
    int s0 = col[e], s1 = col[e + 1], s2 = col[e + 2], s3 = col[e + 3];
    f32x4 h0 = *(const f32x4*)(h + (size_t)s0 * HD + f);
    f32x4 h1 = *(const f32x4*)(h + (size_t)s1 * HD + f);
    f32x4 h2 = *(const f32x4*)(h + (size_t)s2 * HD + f);
    f32x4 h3 = *(const f32x4*)(h + (size_t)s3 * HD + f);
    acc += h0; acc += h1; acc += h2; acc += h3;
  }
  for (; e < end; ++e)
    acc += *(const f32x4*)(h + (size_t)col[e] * HD + f);
  float di = dinv[node];
  f32x4 b = *(const f32x4*)(bias + f);
  acc = acc * di + b;
  u16x4 o;
#pragma unroll
  for (int q = 0; q < 4; ++q) o[q] = f2bf(fmaxf(acc[q], 0.f));
  *(u16x4*)(outb + (size_t)node * HD + f) = o;
}

// -------------------------------------------------------------- pooling (bf16 src, HD cols)
__global__ __launch_bounds__(256) void seg_pool_bf16_k(const unsigned short* __restrict__ src,
                                                       const int* __restrict__ segs,
                                                       const int* __restrict__ sege,
                                                       float* __restrict__ dst, int dstride,
                                                       int doff, int mode) {
  int g = blockIdx.x, f = threadIdx.x;
  int s = segs[g], e = sege[g];
  float a0, a1, a2, a3;
  if (mode == 1) { a0 = a1 = a2 = a3 = -INFINITY; } else { a0 = a1 = a2 = a3 = 0.f; }
  int i = s;
  for (; i + 4 <= e; i += 4) {
    float v0 = bf2f(src[(size_t)(i + 0) * HD + f]);
    float v1 = bf2f(src[(size_t)(i + 1) * HD + f]);
    float v2 = bf2f(src[(size_t)(i + 2) * HD + f]);
    float v3 = bf2f(src[(size_t)(i + 3) * HD + f]);
    if (mode == 1) { a0 = fmaxf(a0, v0); a1 = fmaxf(a1, v1); a2 = fmaxf(a2, v2); a3 = fmaxf(a3, v3); }
    else           { a0 += v0; a1 += v1; a2 += v2; a3 += v3; }
  }
  for (; i < e; ++i) {
    float v = bf2f(src[(size_t)i * HD + f]);
    if (mode == 1) a0 = fmaxf(a0, v); else a0 += v;
  }
  float acc;
  if (mode == 1) acc = fmaxf(fmaxf(a0, a1), fmaxf(a2, a3));
  else {
    acc = (a0 + a1) + (a2 + a3);
    acc /= (float)((e - s) > 0 ? (e - s) : 1);
  }
  dst[(size_t)g * dstride + doff + f] = acc;
}

// ----------------------------------------------------------- small epilogues
// fused: t = prelu(Cd + bl1); pools[768..1023] = prelu(t @ Wl2 + bl2)
__global__ __launch_bounds__(256) void gemm_e_k(const float* __restrict__ Cd,
                                                const float* __restrict__ bl1,
                                                const float* __restrict__ Wl2,
                                                const float* __restrict__ bl2,
                                                const float* __restrict__ pa,
                                                float* __restrict__ pools) {
  __shared__ float t[512];
  int b = blockIdx.x, n = threadIdx.x;
  float a = *pa;
  for (int k = n; k < 512; k += 256) {
    float v = Cd[(size_t)b * 512 + k] + bl1[k];
    t[k] = (v >= 0.f) ? v : a * v;
  }
  __syncthreads();
  float acc = 0.f;
  for (int k = 0; k < 512; ++k) acc = fmaf(t[k], Wl2[k * 256 + n], acc);
  acc += bl2[n];
  acc = (acc >= 0.f) ? acc : a * acc;
  pools[(size_t)b * 1280 + 768 + n] = acc;
}

__global__ __launch_bounds__(256) void final_k(const float* __restrict__ pools,
                                               const float* __restrict__ W5,
                                               const float* __restrict__ b5,
                                               float* __restrict__ out) {
  __shared__ float red[256][4];
  int b = blockIdx.x, t = threadIdx.x;
  float a0 = 0, a1 = 0, a2 = 0, a3 = 0;
  for (int i = t; i < 1280; i += 256) {
    float p = pools[(size_t)b * 1280 + i];
    a0 = fmaf(p, W5[i * 4 + 0], a0);
    a1 = fmaf(p, W5[i * 4 + 1], a1);
    a2 = fmaf(p, W5[i * 4 + 2], a2);
    a3 = fmaf(p, W5[i * 4 + 3], a3);
  }
  red[t][0] = a0; red[t][1] = a1; red[t][2] = a2; red[t][3] = a3;
  __syncthreads();
  for (int off = 128; off >= 1; off >>= 1) {
    if (t < off)
      for (int c = 0; c < 4; ++c) red[t][c] += red[t + off][c];
    __syncthreads();
  }
  if (t == 0) {
    float z[4];
    for (int c = 0; c < 4; ++c) z[c] = red[0][c] + b5[c];
    float m = fmaxf(fmaxf(z[0], z[1]), fmaxf(z[2], z[3]));
    float s = 0.f;
    for (int c = 0; c < 4; ++c) s += expf(z[c] - m);
    float lse = logf(s);
    for (int c = 0; c < 4; ++c) out[b * 4 + c] = z[c] - m - lse;
  }
}

// ================================================================ launcher
extern "C" void kernel_launch(void* const* d_in, const int* in_sizes, int n_in,
                              void* d_out, int out_size, void* d_ws, size_t ws_size,
                              hipStream_t stream) {
  const float* graph_x = (const float*)d_in[0];
  const float* data_x  = (const float*)d_in[2];
  const int*   ei      = (const int*)d_in[3];
  const int*   rei     = (const int*)d_in[4];
  const int*   batch   = (const int*)d_in[5];
  const int*   rooti   = (const int*)d_in[7];
  const float* W1  = (const float*)d_in[8];   const float* b1  = (const float*)d_in[9];
  const float* Wc0 = (const float*)d_in[10];  const float* bc0 = (const float*)d_in[11];
  const float* Wc1 = (const float*)d_in[12];  const float* bc1 = (const float*)d_in[13];
  const float* Wc2 = (const float*)d_in[14];  const float* bc2 = (const float*)d_in[15];
  const float* Wl1 = (const float*)d_in[16];  const float* bl1 = (const float*)d_in[17];
  const float* Wl2 = (const float*)d_in[18];  const float* bl2 = (const float*)d_in[19];
  const float* pa  = (const float*)d_in[20];
  const float* W5  = (const float*)d_in[21];  const float* b5  = (const float*)d_in[22];
  float* out = (float*)d_out;

  char* ws = (char*)d_ws;
  size_t off = 0;
  auto take = [&](size_t bytes) -> void* {
    void* p = ws + off;
    off += (bytes + 255) & ~(size_t)255;
    return p;
  };
  const int NB = ceil_div(NN, 1024);  // 20

  int *deg1, *deg2, *rp1, *rp2, *cur1, *cur2, *col1, *col2, *excl, *bsum, *boff, *segs, *sege;
  float *dv1, *dv2, *hA, *Cd, *pools;
  unsigned short *W1t, *Wc0t, *Wc1t, *Wc2t, *Wl1t, *catb, *hBb, *Axb;

  auto alloc_all = [&](bool withAxb) {
    off = 0;
    deg1 = (int*)take(NN * 4);   deg2 = (int*)take(NN * 4);   // adjacent: one memset
    rp1  = (int*)take((NN + 1) * 4); rp2 = (int*)take((NN + 1) * 4);
    cur1 = (int*)take(NN * 4);   cur2 = (int*)take(NN * 4);
    col1 = (int*)take(EE * 4);   col2 = (int*)take(EE * 4);
    dv1  = (float*)take(NN * 4); dv2  = (float*)take(NN * 4);
    excl = (int*)take((size_t)2 * NN * 4);
    bsum = (int*)take(2 * NB * 4); boff = (int*)take(2 * NB * 4);
    segs = (int*)take(BG * 4);   sege = (int*)take(BG * 4);
    W1t  = (unsigned short*)take((size_t)HD * FIN * 2);
    Wc0t = (unsigned short*)take((size_t)HD * KP * 2);
    Wc1t = (unsigned short*)take((size_t)HD * HD * 2);
    Wc2t = (unsigned short*)take((size_t)HD * HD * 2);
    Wl1t = (unsigned short*)take((size_t)512 * CATK * 2);
    catb = (unsigned short*)take((size_t)BG * CATK * 2);
    Axb  = withAxb ? (unsigned short*)take((size_t)NN * KP * 2) : nullptr;
    hA   = (float*)take((size_t)NN * HD * 4);
    hBb  = (unsigned short*)take((size_t)NN * HD * 2);
    Cd   = (float*)take((size_t)BG * 512 * 4);
    pools = (float*)take((size_t)BG * 1280 * 4);
  };
  alloc_all(true);
  if (off > ws_size) alloc_all(false);
  const bool pathA = (Axb != nullptr);

  // ---- zero-init
  hipMemsetAsync(deg1, 0, (size_t)2 * ((NN * 4 + 255) & ~255), stream);  // deg1+deg2
  hipMemsetAsync(Cd, 0, (size_t)BG * 512 * 4, stream);

  // ---- CSR build (both graphs)
  count_deg2_k<<<ceil_div(2 * EE, 256), 256, 0, stream>>>(ei, rei, deg1, deg2);
  scan_local_k<<<dim3(NB, 2), 1024, 0, stream>>>(deg1, deg2, excl, bsum, NB);
  scan_tops_k<<<1, 64, 0, stream>>>(bsum, boff, rp1 + NN, rp2 + NN, NB);
  scan_add_k<<<dim3(NB, 2), 1024, 0, stream>>>(excl, boff, deg1, deg2, rp1, rp2,
                                               cur1, cur2, dv1, dv2, NB);
  scatter_k<<<dim3(ceil_div(EE, 256), 2), 256, 0, stream>>>(ei, rei, cur1, cur2, col1, col2);
  segbounds_k<<<ceil_div(NN, 256), 256, 0, stream>>>(batch, segs, sege, NN);

  // ---- weight transposes (batched, 6720 blocks)
  trans_k<<<6720, 256, 0, stream>>>(W1, W1t, Wc0, Wc0t, Wc1, Wc1t, Wc2, Wc2t, Wl1, Wl1t);

  // ---- data_x convert + fused segment-mean + root rows -> cat
  conv_pool_k<<<dim3(BG, KP / 256 + ceil_div(CATK - RAWF, 256)), 256, 0, stream>>>(
      data_x, Axb, catb, segs, sege, rooti);

  int mt = ceil_div(NN, 128);  // 157

  // ---- branch 1: GCN(graph_x) -> relu -> segment_max (A read direct as f32)
  hipMemsetAsync(hA, 0, (size_t)NN * HD * 4, stream);
  gemm_k<false><<<dim3(2, mt, 2), 256, 0, stream>>>(graph_x, FIN, W1t, FIN, hA, dv1,
                                                    NN, HD, FIN, 384, 1);
  gcn_agg_k<<<ceil_div(NN, 4), 256, 0, stream>>>(hA, rp1, col1, dv1, b1, hBb, NN);
  seg_pool_bf16_k<<<BG, 256, 0, stream>>>(hBb, segs, sege, pools, 1280, 1024, 1);

  // ---- branch 3 layer 0 (the big one)
  hipMemsetAsync(hA, 0, (size_t)NN * HD * 4, stream);
  if (pathA)
    gemm_k<true><<<dim3(2, mt, 2), 256, 0, stream>>>(Axb, KP, Wc0t, KP, hA, dv2,
                                                     NN, HD, KP, 2560, 1);
  else
    gemm_k<false><<<dim3(2, mt, 4), 256, 0, stream>>>(data_x, RAWF, Wc0t, KP, hA, dv2,
                                                      NN, HD, RAWF, 1256, 1);
  gcn_agg_k<<<ceil_div(NN, 4), 256, 0, stream>>>(hA, rp2, col2, dv2, bc0, hBb, NN);
  seg_pool_bf16_k<<<BG, 256, 0, stream>>>(hBb, segs, sege, pools, 1280, 0, 0);

  // ---- branch 3 layer 1
  hipMemsetAsync(hA, 0, (size_t)NN * HD * 4, stream);
  gemm_k<true><<<dim3(2, mt, 2), 256, 0, stream>>>(hBb, HD, Wc1t, HD, hA, dv2,
                                                   NN, HD, HD, 128, 1);
  gcn_agg_k<<<ceil_div(NN, 4), 256, 0, stream>>>(hA, rp2, col2, dv2, bc1, hBb, NN);
  seg_pool_bf16_k<<<BG, 256, 0, stream>>>(hBb, segs, sege, pools, 1280, 256, 0);

  // ---- branch 3 layer 2
  hipMemsetAsync(hA, 0, (size_t)NN * HD * 4, stream);
  gemm_k<true><<<dim3(2, mt, 2), 256, 0, stream>>>(hBb, HD, Wc2t, HD, hA, dv2,
                                                   NN, HD, HD, 128, 1);
  gcn_agg_k<<<ceil_div(NN, 4), 256, 0, stream>>>(hA, rp2, col2, dv2, bc2, hBb, NN);
  seg_pool_bf16_k<<<BG, 256, 0, stream>>>(hBb, segs, sege, pools, 1280, 512, 0);

  // ---- branch 2: cat @ Wl1 (split-K 32) -> prelu -> @ Wl2 -> prelu (fused)
  gemm_k<true><<<dim3(4, 1, 32), 256, 0, stream>>>(catb, CATK, Wl1t, CATK, Cd, nullptr,
                                                   BG, 512, CATK, 320, 1);
  gemm_e_k<<<BG, 256, 0, stream>>>(Cd, bl1, Wl2, bl2, pa, pools);

  // ---- final concat @ W5 + log_softmax
  final_k<<<BG, 256, 0, stream>>>(pools, W5, b5, out);
}

// Round 3
// 1197.778 us; speedup vs baseline: 1.1429x; 1.1324x over previous
//
#include <hip/hip_runtime.h>
#include <math.h>

// Problem dims (fixed by reference setup_inputs)
#define NN   20000   // nodes
#define BG   128     // graphs
#define EE   320000  // edges
#define FIN  768
#define RAWF 5000
#define KP   5120    // padded raw K (mult of 32)
#define CATK 10240   // padded 2*RAWF
#define HD   256
#define NC   4

typedef __attribute__((ext_vector_type(4))) float          f32x4;
typedef __attribute__((ext_vector_type(8))) unsigned short u16x8;
typedef __attribute__((ext_vector_type(4))) unsigned short u16x4;
typedef __attribute__((ext_vector_type(8))) __bf16         bf16x8;

__device__ __forceinline__ unsigned short f2bf(float f) {
  unsigned u = __float_as_uint(f);
  u += 0x7FFFu + ((u >> 16) & 1u);
  return (unsigned short)(u >> 16);
}
__device__ __forceinline__ float bf2f(unsigned short u) {
  return __uint_as_float((unsigned)u << 16);
}

static inline int ceil_div(int a, int b) { return (a + b - 1) / b; }

// ---------------------------------------------------------------- CSR build
__global__ void count_deg2_k(const int* __restrict__ ei, const int* __restrict__ rei,
                             int* __restrict__ deg1, int* __restrict__ deg2) {
  int i = blockIdx.x * 256 + threadIdx.x;
  if (i < EE) atomicAdd(&deg1[ei[EE + i]], 1);
  else if (i < 2 * EE) atomicAdd(&deg2[rei[i]], 1);  // rei[EE + (i-EE)] == rei[i]
}

__global__ __launch_bounds__(1024) void scan_local_k(const int* __restrict__ deg1,
                                                     const int* __restrict__ deg2,
                                                     int* __restrict__ excl,
                                                     int* __restrict__ bsum, int nb) {
  const int* deg = blockIdx.y ? deg2 : deg1;
  int* ex = excl + (size_t)blockIdx.y * NN;
  int* bs = bsum + (size_t)blockIdx.y * nb;
  __shared__ int wsum[16];
  int t = threadIdx.x, lane = t & 63, w = t >> 6;
  int i = blockIdx.x * 1024 + t;
  int v = (i < NN) ? deg[i] : 0;
  int acc = v;
#pragma unroll
  for (int off = 1; off < 64; off <<= 1) {
    int o = __shfl_up(acc, off, 64);
    if (lane >= off) acc += o;
  }
  if (lane == 63) wsum[w] = acc;
  __syncthreads();
  if (w == 0 && lane < 16) {
    int s = wsum[lane];
#pragma unroll
    for (int off = 1; off < 16; off <<= 1) {
      int o = __shfl_up(s, off, 64);
      if (lane >= off) s += o;
    }
    wsum[lane] = s;
  }
  __syncthreads();
  if (w > 0) acc += wsum[w - 1];
  if (i < NN) ex[i] = acc - v;
  if (t == 1023) bs[blockIdx.x] = acc;
}

// parallel top-level scan: 2 graphs in the two 32-lane halves of one wave
__global__ void scan_tops_k(const int* __restrict__ bsum, int* __restrict__ boff,
                            int* __restrict__ end1, int* __restrict__ end2, int nb) {
  int t = threadIdx.x;           // 64 threads
  int half = t >> 5, idx = t & 31;
  int v = (idx < nb) ? bsum[half * nb + idx] : 0;
  int acc = v;
#pragma unroll
  for (int off = 1; off < 32; off <<= 1) {
    int o = __shfl_up(acc, off, 32);
    if (idx >= off) acc += o;
  }
  if (idx < nb) boff[half * nb + idx] = acc - v;   // exclusive
  if (idx == nb - 1) {
    if (half == 0) *end1 = acc; else *end2 = acc;
  }
}

// + fused segbounds (y==0 threads)
__global__ __launch_bounds__(1024) void scan_add_k(
    const int* __restrict__ excl, const int* __restrict__ boff,
    const int* __restrict__ deg1, const int* __restrict__ deg2,
    int* __restrict__ rp1, int* __restrict__ rp2,
    int* __restrict__ cur1, int* __restrict__ cur2,
    float* __restrict__ dv1, float* __restrict__ dv2,
    const int* __restrict__ batch, int* __restrict__ segs, int* __restrict__ sege,
    int nb) {
  int y = blockIdx.y;
  const int* deg = y ? deg2 : deg1;
  int* rp = y ? rp2 : rp1;
  int* cur = y ? cur2 : cur1;
  float* dv = y ? dv2 : dv1;
  int i = blockIdx.x * 1024 + threadIdx.x;
  if (i < NN) {
    int v = excl[(size_t)y * NN + i] + boff[y * nb + blockIdx.x];
    rp[i] = v;
    cur[i] = v;
    dv[i] = rsqrtf((float)(deg[i] + 1));
    if (y == 0) {
      int b = batch[i];
      if (i == 0 || batch[i - 1] != b) segs[b] = i;
      if (i == NN - 1 || batch[i + 1] != b) sege[b] = i + 1;
    }
  }
}

__global__ void scatter_k(const int* __restrict__ ei, const int* __restrict__ rei,
                          int* __restrict__ cur1, int* __restrict__ cur2,
                          int* __restrict__ col1, int* __restrict__ col2) {
  int i = blockIdx.x * 256 + threadIdx.x;
  int y = blockIdx.y;
  if (i < EE) {
    const int* e = y ? rei : ei;
    int* cur = y ? cur2 : cur1;
    int* col = y ? col2 : col1;
    int d = e[EE + i];
    int p = atomicAdd(&cur[d], 1);
    col[p] = e[i];
  }
}

// ------------------------------------------------- batched weight transpose
__global__ __launch_bounds__(256) void trans_k(
    const float* __restrict__ i0, unsigned short* __restrict__ o0,   // W1  768x256 ->768
    const float* __restrict__ i1, unsigned short* __restrict__ o1,   // Wc0 5000x256 ->5120
    const float* __restrict__ i2, unsigned short* __restrict__ o2,   // Wc1 256x256
    const float* __restrict__ i3, unsigned short* __restrict__ o3,   // Wc2 256x256
    const float* __restrict__ i4, unsigned short* __restrict__ o4) { // Wl1 10000x512 ->10240
  __shared__ unsigned short tile[32][34];
  int b = blockIdx.x;
  const float* in; unsigned short* out;
  int K, N, Kout, tx, lid;
  if (b < 192)        { in=i0; out=o0; K=768;   N=256; Kout=768;   tx=24;  lid=b; }
  else if (b < 1472)  { in=i1; out=o1; K=5000;  N=256; Kout=5120;  tx=160; lid=b-192; }
  else if (b < 1536)  { in=i2; out=o2; K=256;   N=256; Kout=256;   tx=8;   lid=b-1472; }
  else if (b < 1600)  { in=i3; out=o3; K=256;   N=256; Kout=256;   tx=8;   lid=b-1536; }
  else                { in=i4; out=o4; K=10000; N=512; Kout=10240; tx=320; lid=b-1600; }
  int k0 = (lid % tx) * 32, n0 = (lid / tx) * 32;
  int txx = threadIdx.x & 31, tyy = threadIdx.x >> 5;
#pragma unroll
  for (int r = 0; r < 32; r += 8) {
    int k = k0 + tyy + r, n = n0 + txx;
    float v = (k < K) ? in[(size_t)k * N + n] : 0.f;
    tile[tyy + r][txx] = f2bf(v);
  }
  __syncthreads();
#pragma unroll
  for (int r = 0; r < 32; r += 8) {
    int n = n0 + tyy + r, k = k0 + txx;
    out[(size_t)n * Kout + k] = tile[txx][tyy + r];
  }
}

// data_x fp32 -> (optional) bf16 K-padded copy + fused segment-mean -> cat[:, :5000]
// grid (BG, 20 + 21): y<20 = pool/convert chunks; y>=20 = root-row -> cat right half.
__global__ __launch_bounds__(256) void conv_pool_k(const float* __restrict__ x,
                                                   unsigned short* __restrict__ xb,
                                                   unsigned short* __restrict__ cat,
                                                   const int* __restrict__ segs,
                                                   const int* __restrict__ sege,
                                                   const int* __restrict__ root) {
  int g = blockIdx.x;
  if (blockIdx.y >= KP / 256) {   // ---- root-cat part (cols 5000..10239)
    int c = (blockIdx.y - KP / 256) * 256 + threadIdx.x;
    if (c < CATK - RAWF) {
      unsigned short v = 0;
      if (c < RAWF) v = f2bf(x[(size_t)root[g] * RAWF + c]);
      cat[(size_t)g * CATK + RAWF + c] = v;
    }
    return;
  }
  __shared__ f32x4 part[4][64];
  int wave = threadIdx.x >> 6, lane = threadIdx.x & 63;
  int c = blockIdx.y * 256 + lane * 4;
  int s = segs[g], e = sege[g];
  bool v4 = (c + 4 <= RAWF);      // RAWF%4==0: vectors are fully valid or fully pad
  f32x4 sum = (f32x4)0.f;
  for (int i = s + wave; i < e; i += 4) {
    f32x4 v = (f32x4)0.f;
    if (v4) v = *(const f32x4*)(x + (size_t)i * RAWF + c);
    if (xb) {
      u16x4 h;
      h[0] = f2bf(v[0]); h[1] = f2bf(v[1]); h[2] = f2bf(v[2]); h[3] = f2bf(v[3]);
      *(u16x4*)(xb + (size_t)i * KP + c) = h;
    }
    sum += v;
  }
  part[wave][lane] = sum;
  __syncthreads();
  if (threadIdx.x < 64 && v4) {
    f32x4 tot = part[0][lane] + part[1][lane] + part[2][lane] + part[3][lane];
    float cnt = (float)(e - s);
    u16x4 o;
    o[0] = f2bf(tot[0] / cnt); o[1] = f2bf(tot[1] / cnt);
    o[2] = f2bf(tot[2] / cnt); o[3] = f2bf(tot[3] / cnt);
    *(u16x4*)(cat + (size_t)g * CATK + c) = o;
  }
}

// ------------------------------------------------------------- MFMA GEMM
// C[M][N] (+)= A[M][K] @ Bt[N][K]bf16, optional per-row scale (escale[row]).
// Output: Cb!=null -> non-atomic bf16 store (requires gridDim.z==1);
//         else atomic_out -> f32 atomicAdd; else plain f32 store.
// 128x128x32 tile, 4 waves, register-prefetch pipeline.
// gridDim.x==2: remap (x,y) so the x-pair of the same A panel lands on the
// SAME XCD (dispatch linear id %8 = XCD; pair ids differ by exactly 8).
template <bool ABF16>
__global__ __launch_bounds__(256) void gemm_k(
    const void* __restrict__ Av, int Astride,
    const unsigned short* __restrict__ Bt, int Bstride,
    float* __restrict__ C, unsigned short* __restrict__ Cb,
    const float* __restrict__ escale,
    int M, int N, int Kreal, int kchunk, int atomic_out) {
  __shared__ unsigned short As[128 * 40];  // pad 32->40: 2-way bank alias only
  __shared__ unsigned short Bs[128 * 40];
  const int tid = threadIdx.x;
  const int lane = tid & 63, wave = tid >> 6;
  const int quad = lane >> 4, l16 = lane & 15;
  const int koff = quad * 8;

  int xt = blockIdx.x, yt = blockIdx.y;
  if (gridDim.x == 2) {
    const int MT = gridDim.y;
    int flat = (yt << 1) | xt;
    int gp = flat >> 4;
    int ybase = gp << 3;
    int rem = MT - ybase;
    int j = flat & 15;
    if (rem >= 8) { xt = j >> 3; yt = ybase + (j & 7); }
    else          { xt = (j >= rem); yt = ybase + (xt ? j - rem : j); }
  }
  const int bn = xt * 128, bm = yt * 128;
  const int wm = (wave >> 1) * 64, wn = (wave & 1) * 64;
  const int kbegin = blockIdx.z * kchunk;
  int kend = kbegin + kchunk; if (kend > Kreal) kend = Kreal;

  const int brow = tid >> 2, bcol = (tid & 3) * 8;      // bf16 16B loads, 2 rounds
  const int arow_f = tid >> 3, acol_f = (tid & 7) * 4;  // f32 16B loads, 4 rounds

  u16x8 pb[2];
  u16x8 pa_b[2];
  f32x4 pa_f[4];

  auto load_tile = [&](int k0) {
#pragma unroll
    for (int i = 0; i < 2; ++i) {
      int gk = k0 + bcol;
      bool ok = ABF16 ? true : (gk + 8 <= kend);  // B K-dim padded for bf16 paths
      u16x8 v = (u16x8)(unsigned short)0;
      if (ok) v = *(const u16x8*)(Bt + (size_t)(bn + i * 64 + brow) * Bstride + gk);
      pb[i] = v;
    }
    if (ABF16) {
      const unsigned short* A = (const unsigned short*)Av;
#pragma unroll
      for (int i = 0; i < 2; ++i) {
        int r = bm + i * 64 + brow;
        u16x8 v = (u16x8)(unsigned short)0;
        if (r < M) v = *(const u16x8*)(A + (size_t)r * Astride + k0 + bcol);
        pa_b[i] = v;
      }
    } else {
      const float* A = (const float*)Av;
#pragma unroll
      for (int i = 0; i < 4; ++i) {
        int r = bm + i * 32 + arow_f;
        int gk = k0 + acol_f;
        f32x4 v = (f32x4)0.f;
        if (r < M && gk + 4 <= kend) v = *(const f32x4*)(A + (size_t)r * Astride + gk);
        pa_f[i] = v;
      }
    }
  };
  auto store_tile = [&]() {
#pragma unroll
    for (int i = 0; i < 2; ++i)
      *(u16x8*)&Bs[(i * 64 + brow) * 40 + bcol] = pb[i];
    if (ABF16) {
#pragma unroll
      for (int i = 0; i < 2; ++i)
        *(u16x8*)&As[(i * 64 + brow) * 40 + bcol] = pa_b[i];
    } else {
#pragma unroll
      for (int i = 0; i < 4; ++i) {
        u16x4 h;
        h[0] = f2bf(pa_f[i][0]); h[1] = f2bf(pa_f[i][1]);
        h[2] = f2bf(pa_f[i][2]); h[3] = f2bf(pa_f[i][3]);
        *(u16x4*)&As[(i * 32 + arow_f) * 40 + acol_f] = h;
      }
    }
  };

  f32x4 acc[4][4] = {};
  load_tile(kbegin);
  for (int k0 = kbegin; k0 < kend; k0 += 32) {
    store_tile();
    __syncthreads();
    int k1 = k0 + 32;
    if (k1 < kend) load_tile(k1);  // prefetch: latency overlaps MFMA below
    u16x8 ar[4], br[4];
#pragma unroll
    for (int i = 0; i < 4; ++i) ar[i] = *(const u16x8*)&As[(wm + i * 16 + l16) * 40 + koff];
#pragma unroll
    for (int j = 0; j < 4; ++j) br[j] = *(const u16x8*)&Bs[(wn + j * 16 + l16) * 40 + koff];
#pragma unroll
    for (int i = 0; i < 4; ++i)
#pragma unroll
      for (int j = 0; j < 4; ++j)
        acc[i][j] = __builtin_amdgcn_mfma_f32_16x16x32_bf16(
            __builtin_bit_cast(bf16x8, ar[i]), __builtin_bit_cast(bf16x8, br[j]),
            acc[i][j], 0, 0, 0);
    __syncthreads();
  }
  // epilogue: D[row=quad*4+rr][col=l16] (m89/m91-verified mapping)
#pragma unroll
  for (int i = 0; i < 4; ++i)
#pragma unroll
    for (int rr = 0; rr < 4; ++rr) {
      int grow = bm + wm + i * 16 + quad * 4 + rr;
      if (grow >= M) continue;
      float sc = escale ? escale[grow] : 1.f;
#pragma unroll
      for (int j = 0; j < 4; ++j) {
        int gcol = bn + wn + j * 16 + l16;
        if (gcol >= N) continue;
        float v = acc[i][j][rr] * sc;
        if (Cb) Cb[(size_t)grow * N + gcol] = f2bf(v);
        else if (atomic_out) atomicAdd(&C[(size_t)grow * N + gcol], v);
        else C[(size_t)grow * N + gcol] = v;
      }
    }
}

// f32 h -> bf16 h (for the atomic split-K layer only)
__global__ void conv_h_k(const float* __restrict__ in, unsigned short* __restrict__ out) {
  size_t i = (size_t)(blockIdx.x * 256 + threadIdx.x) * 8;  // grid sized exactly
  f32x4 a = *(const f32x4*)(in + i);
  f32x4 b = *(const f32x4*)(in + i + 4);
  u16x8 o;
  o[0]=f2bf(a[0]); o[1]=f2bf(a[1]); o[2]=f2bf(a[2]); o[3]=f2bf(a[3]);
  o[4]=f2bf(b[0]); o[5]=f2bf(b[1]); o[6]=f2bf(b[2]); o[7]=f2bf(b[3]);
  *(u16x8*)(out + i) = o;
}

// ------------------------------------------------------------ GCN aggregate
// hb is bf16, PRE-SCALED by dinv: h' = dinv .* (x@W).
// out[i] = relu(dinv[i]*(h'[i] + sum_in h'[s]) + bias), bf16 out.
__global__ __launch_bounds__(256) void gcn_agg_k(
    const unsigned short* __restrict__ hb, const int* __restrict__ rowptr,
    const int* __restrict__ col, const float* __restrict__ dinv,
    const float* __restrict__ bias, unsigned short* __restrict__ outb, int n) {
  int wave = threadIdx.x >> 6, lane = threadIdx.x & 63;
  int node = blockIdx.x * 4 + wave;
  if (node >= n) return;
  int f = lane * 4;
  u16x4 sv = *(const u16x4*)(hb + (size_t)node * HD + f);  // self loop (pre-scaled)
  f32x4 acc;
  acc[0] = bf2f(sv[0]); acc[1] = bf2f(sv[1]); acc[2] = bf2f(sv[2]); acc[3] = bf2f(sv[3]);
  int beg = rowptr[node], end = rowptr[node + 1];
  int e = beg;
  for (; e + 4 <= end; e += 4) {
    int s0 = col[e], s1 = col[e + 1], s2 = col[e + 2], s3 = col[e + 3];
    u16x4 h0 = *(const u16x4*)(hb + (size_t)s0 * HD + f);
    u16x4 h1 = *(const u16x4*)(hb + (size_t)s1 * HD + f);
    u16x4 h2 = *(const u16x4*)(hb + (size_t)s2 * HD + f);
    u16x4 h3 = *(const u16x4*)(hb + (size_t)s3 * HD + f);
#pragma unroll
    for (int q = 0; q < 4; ++q)
      acc[q] += bf2f(h0[q]) + bf2f(h1[q]) + bf2f(h2[q]) + bf2f(h3[q]);
  }
  for (; e < end; ++e) {
    u16x4 h0 = *(const u16x4*)(hb + (size_t)col[e] * HD + f);
#pragma unroll
    for (int q = 0; q < 4; ++q) acc[q] += bf2f(h0[q]);
  }
  float di = dinv[node];
  f32x4 b = *(const f32x4*)(bias + f);
  acc = acc * di + b;
  u16x4 o;
#pragma unroll
  for (int q = 0; q < 4; ++q) o[q] = f2bf(fmaxf(acc[q], 0.f));
  *(u16x4*)(outb + (size_t)node * HD + f) = o;
}

// -------------------------------------------------------------- pooling (bf16 src, HD cols)
__global__ __launch_bounds__(256) void seg_pool_bf16_k(const unsigned short* __restrict__ src,
                                                       const int* __restrict__ segs,
                                                       const int* __restrict__ sege,
                                                       float* __restrict__ dst, int dstride,
                                                       int doff, int mode) {
  int g = blockIdx.x, f = threadIdx.x;
  int s = segs[g], e = sege[g];
  float a0, a1, a2, a3;
  if (mode == 1) { a0 = a1 = a2 = a3 = -INFINITY; } else { a0 = a1 = a2 = a3 = 0.f; }
  int i = s;
  for (; i + 4 <= e; i += 4) {
    float v0 = bf2f(src[(size_t)(i + 0) * HD + f]);
    float v1 = bf2f(src[(size_t)(i + 1) * HD + f]);
    float v2 = bf2f(src[(size_t)(i + 2) * HD + f]);
    float v3 = bf2f(src[(size_t)(i + 3) * HD + f]);
    if (mode == 1) { a0 = fmaxf(a0, v0); a1 = fmaxf(a1, v1); a2 = fmaxf(a2, v2); a3 = fmaxf(a3, v3); }
    else           { a0 += v0; a1 += v1; a2 += v2; a3 += v3; }
  }
  for (; i < e; ++i) {
    float v = bf2f(src[(size_t)i * HD + f]);
    if (mode == 1) a0 = fmaxf(a0, v); else a0 += v;
  }
  float acc;
  if (mode == 1) acc = fmaxf(fmaxf(a0, a1), fmaxf(a2, a3));
  else {
    acc = (a0 + a1) + (a2 + a3);
    acc /= (float)((e - s) > 0 ? (e - s) : 1);
  }
  dst[(size_t)g * dstride + doff + f] = acc;
}

// ----------------------------------------------------------- small epilogues
// fused: t = prelu(Cd + bl1); pools[768..1023] = prelu(t @ Wl2 + bl2)
__global__ __launch_bounds__(256) void gemm_e_k(const float* __restrict__ Cd,
                                                const float* __restrict__ bl1,
                                                const float* __restrict__ Wl2,
                                                const float* __restrict__ bl2,
                                                const float* __restrict__ pa,
                                                float* __restrict__ pools) {
  __shared__ float t[512];
  int b = blockIdx.x, n = threadIdx.x;
  float a = *pa;
  for (int k = n; k < 512; k += 256) {
    float v = Cd[(size_t)b * 512 + k] + bl1[k];
    t[k] = (v >= 0.f) ? v : a * v;
  }
  __syncthreads();
  float acc = 0.f;
  for (int k = 0; k < 512; ++k) acc = fmaf(t[k], Wl2[k * 256 + n], acc);
  acc += bl2[n];
  acc = (acc >= 0.f) ? acc : a * acc;
  pools[(size_t)b * 1280 + 768 + n] = acc;
}

__global__ __launch_bounds__(256) void final_k(const float* __restrict__ pools,
                                               const float* __restrict__ W5,
                                               const float* __restrict__ b5,
                                               float* __restrict__ out) {
  __shared__ float red[256][4];
  int b = blockIdx.x, t = threadIdx.x;
  float a0 = 0, a1 = 0, a2 = 0, a3 = 0;
  for (int i = t; i < 1280; i += 256) {
    float p = pools[(size_t)b * 1280 + i];
    a0 = fmaf(p, W5[i * 4 + 0], a0);
    a1 = fmaf(p, W5[i * 4 + 1], a1);
    a2 = fmaf(p, W5[i * 4 + 2], a2);
    a3 = fmaf(p, W5[i * 4 + 3], a3);
  }
  red[t][0] = a0; red[t][1] = a1; red[t][2] = a2; red[t][3] = a3;
  __syncthreads();
  for (int off = 128; off >= 1; off >>= 1) {
    if (t < off)
      for (int c = 0; c < 4; ++c) red[t][c] += red[t + off][c];
    __syncthreads();
  }
  if (t == 0) {
    float z[4];
    for (int c = 0; c < 4; ++c) z[c] = red[0][c] + b5[c];
    float m = fmaxf(fmaxf(z[0], z[1]), fmaxf(z[2], z[3]));
    float s = 0.f;
    for (int c = 0; c < 4; ++c) s += expf(z[c] - m);
    float lse = logf(s);
    for (int c = 0; c < 4; ++c) out[b * 4 + c] = z[c] - m - lse;
  }
}

// ================================================================ launcher
extern "C" void kernel_launch(void* const* d_in, const int* in_sizes, int n_in,
                              void* d_out, int out_size, void* d_ws, size_t ws_size,
                              hipStream_t stream) {
  const float* graph_x = (const float*)d_in[0];
  const float* data_x  = (const float*)d_in[2];
  const int*   ei      = (const int*)d_in[3];
  const int*   rei     = (const int*)d_in[4];
  const int*   batch   = (const int*)d_in[5];
  const int*   rooti   = (const int*)d_in[7];
  const float* W1  = (const float*)d_in[8];   const float* b1  = (const float*)d_in[9];
  const float* Wc0 = (const float*)d_in[10];  const float* bc0 = (const float*)d_in[11];
  const float* Wc1 = (const float*)d_in[12];  const float* bc1 = (const float*)d_in[13];
  const float* Wc2 = (const float*)d_in[14];  const float* bc2 = (const float*)d_in[15];
  const float* Wl1 = (const float*)d_in[16];  const float* bl1 = (const float*)d_in[17];
  const float* Wl2 = (const float*)d_in[18];  const float* bl2 = (const float*)d_in[19];
  const float* pa  = (const float*)d_in[20];
  const float* W5  = (const float*)d_in[21];  const float* b5  = (const float*)d_in[22];
  float* out = (float*)d_out;

  char* ws = (char*)d_ws;
  size_t off = 0;
  auto take = [&](size_t bytes) -> void* {
    void* p = ws + off;
    off += (bytes + 255) & ~(size_t)255;
    return p;
  };
  const int NB = ceil_div(NN, 1024);  // 20

  int *deg1, *deg2, *rp1, *rp2, *cur1, *cur2, *col1, *col2, *excl, *bsum, *boff, *segs, *sege;
  float *dv1, *dv2, *hA, *Cd, *pools;
  unsigned short *W1t, *Wc0t, *Wc1t, *Wc2t, *Wl1t, *catb, *hAb, *hBb, *Axb;

  auto alloc_all = [&](bool withAxb) {
    off = 0;
    // deg1, deg2, Cd first and contiguous: single memset covers all three
    deg1 = (int*)take(NN * 4);   deg2 = (int*)take(NN * 4);
    Cd   = (float*)take((size_t)BG * 512 * 4);
    rp1  = (int*)take((NN + 1) * 4); rp2 = (int*)take((NN + 1) * 4);
    cur1 = (int*)take(NN * 4);   cur2 = (int*)take(NN * 4);
    col1 = (int*)take(EE * 4);   col2 = (int*)take(EE * 4);
    dv1  = (float*)take(NN * 4); dv2  = (float*)take(NN * 4);
    excl = (int*)take((size_t)2 * NN * 4);
    bsum = (int*)take(2 * NB * 4); boff = (int*)take(2 * NB * 4);
    segs = (int*)take(BG * 4);   sege = (int*)take(BG * 4);
    W1t  = (unsigned short*)take((size_t)HD * FIN * 2);
    Wc0t = (unsigned short*)take((size_t)HD * KP * 2);
    Wc1t = (unsigned short*)take((size_t)HD * HD * 2);
    Wc2t = (unsigned short*)take((size_t)HD * HD * 2);
    Wl1t = (unsigned short*)take((size_t)512 * CATK * 2);
    catb = (unsigned short*)take((size_t)BG * CATK * 2);
    Axb  = withAxb ? (unsigned short*)take((size_t)NN * KP * 2) : nullptr;
    hA   = (float*)take((size_t)NN * HD * 4);
    hAb  = (unsigned short*)take((size_t)NN * HD * 2);
    hBb  = (unsigned short*)take((size_t)NN * HD * 2);
    pools = (float*)take((size_t)BG * 1280 * 4);
  };
  alloc_all(true);
  if (off > ws_size) alloc_all(false);
  const bool pathA = (Axb != nullptr);

  // ---- zero-init: deg1+deg2+Cd in one contiguous memset
  const size_t degpad = ((size_t)NN * 4 + 255) & ~(size_t)255;
  hipMemsetAsync(deg1, 0, degpad * 2 + (size_t)BG * 512 * 4, stream);

  // ---- CSR build (both graphs) + segbounds fused into scan_add
  count_deg2_k<<<ceil_div(2 * EE, 256), 256, 0, stream>>>(ei, rei, deg1, deg2);
  scan_local_k<<<dim3(NB, 2), 1024, 0, stream>>>(deg1, deg2, excl, bsum, NB);
  scan_tops_k<<<1, 64, 0, stream>>>(bsum, boff, rp1 + NN, rp2 + NN, NB);
  scan_add_k<<<dim3(NB, 2), 1024, 0, stream>>>(excl, boff, deg1, deg2, rp1, rp2,
                                               cur1, cur2, dv1, dv2,
                                               batch, segs, sege, NB);
  scatter_k<<<dim3(ceil_div(EE, 256), 2), 256, 0, stream>>>(ei, rei, cur1, cur2, col1, col2);

  // ---- weight transposes (batched, 6720 blocks)
  trans_k<<<6720, 256, 0, stream>>>(W1, W1t, Wc0, Wc0t, Wc1, Wc1t, Wc2, Wc2t, Wl1, Wl1t);

  // ---- data_x convert + fused segment-mean + root rows -> cat
  conv_pool_k<<<dim3(BG, KP / 256 + ceil_div(CATK - RAWF, 256)), 256, 0, stream>>>(
      data_x, Axb, catb, segs, sege, rooti);

  int mt = ceil_div(NN, 128);  // 157

  // ---- branch 1: GCN(graph_x) -> relu -> segment_max
  // z=1: non-atomic, bf16 h' written directly (no memset, no atomics)
  gemm_k<false><<<dim3(2, mt, 1), 256, 0, stream>>>(graph_x, FIN, W1t, FIN,
                                                    nullptr, hAb, dv1,
                                                    NN, HD, FIN, FIN, 0);
  gcn_agg_k<<<ceil_div(NN, 4), 256, 0, stream>>>(hAb, rp1, col1, dv1, b1, hBb, NN);
  seg_pool_bf16_k<<<BG, 256, 0, stream>>>(hBb, segs, sege, pools, 1280, 1024, 1);

  // ---- branch 3 layer 0 (the big one): split-K atomics f32, then bf16 convert
  hipMemsetAsync(hA, 0, (size_t)NN * HD * 4, stream);
  if (pathA)
    gemm_k<true><<<dim3(2, mt, 2), 256, 0, stream>>>(Axb, KP, Wc0t, KP, hA, nullptr, dv2,
                                                     NN, HD, KP, 2560, 1);
  else
    gemm_k<false><<<dim3(2, mt, 4), 256, 0, stream>>>(data_x, RAWF, Wc0t, KP, hA, nullptr, dv2,
                                                      NN, HD, RAWF, 1280, 1);
  conv_h_k<<<(NN * HD) / (256 * 8), 256, 0, stream>>>(hA, hAb);
  gcn_agg_k<<<ceil_div(NN, 4), 256, 0, stream>>>(hAb, rp2, col2, dv2, bc0, hBb, NN);
  seg_pool_bf16_k<<<BG, 256, 0, stream>>>(hBb, segs, sege, pools, 1280, 0, 0);

  // ---- branch 3 layer 1 (z=1, direct bf16 out)
  gemm_k<true><<<dim3(2, mt, 1), 256, 0, stream>>>(hBb, HD, Wc1t, HD,
                                                   nullptr, hAb, dv2,
                                                   NN, HD, HD, HD, 0);
  gcn_agg_k<<<ceil_div(NN, 4), 256, 0, stream>>>(hAb, rp2, col2, dv2, bc1, hBb, NN);
  seg_pool_bf16_k<<<BG, 256, 0, stream>>>(hBb, segs, sege, pools, 1280, 256, 0);

  // ---- branch 3 layer 2 (z=1, direct bf16 out)
  gemm_k<true><<<dim3(2, mt, 1), 256, 0, stream>>>(hBb, HD, Wc2t, HD,
                                                   nullptr, hAb, dv2,
                                                   NN, HD, HD, HD, 0);
  gcn_agg_k<<<ceil_div(NN, 4), 256, 0, stream>>>(hAb, rp2, col2, dv2, bc2, hBb, NN);
  seg_pool_bf16_k<<<BG, 256, 0, stream>>>(hBb, segs, sege, pools, 1280, 512, 0);

  // ---- branch 2: cat @ Wl1 (split-K 32) -> prelu -> @ Wl2 -> prelu (fused)
  gemm_k<true><<<dim3(4, 1, 32), 256, 0, stream>>>(catb, CATK, Wl1t, CATK, Cd, nullptr, nullptr,
                                                   BG, 512, CATK, 320, 1);
  gemm_e_k<<<BG, 256, 0, stream>>>(Cd, bl1, Wl2, bl2, pa, pools);

  // ---- final concat @ W5 + log_softmax
  final_k<<<BG, 256, 0, stream>>>(pools, W5, b5, out);
}